// Round 16
// baseline (167.243 us; speedup 1.0000x reference)
//
#include <hip/hip_runtime.h>

#define HD 1024
#define ID 4096
#define NR 8192

typedef float f32x4 __attribute__((ext_vector_type(4)));
typedef __bf16 bf16x8 __attribute__((ext_vector_type(8)));
typedef int i32x8 __attribute__((ext_vector_type(8)));

__device__ inline ushort f2bf(float f) {
    union { float f; unsigned u; } v; v.f = f;
    unsigned u = v.u;
    unsigned r = (u + 0x7fffu + ((u >> 16) & 1u)) >> 16;  // RNE
    return (ushort)r;
}

__device__ inline float wave_sum(float v) {
#pragma unroll
    for (int o = 32; o > 0; o >>= 1) v += __shfl_xor(v, o, 64);
    return v;
}

// YOSO activation: t = 1 - acos(s)/pi via A&S 4.4.45 (|err| <= 6.7e-5 rad), out t^9.
__device__ __forceinline__ float yoso_act(float v) {
    float s = fminf(fmaxf(v, -0.999999f), 0.999999f);
    float a = fabsf(s);
    float p = 0.49998557f + a * (-0.06751706f + a * (0.02363794f - a * 0.00596170f));
    float q = sqrtf(1.0f - a) * p;           // acos(|s|)/pi
    float tt = (s >= 0.0f) ? 1.0f - q : q;
    float t2 = tt * tt, t4 = t2 * t2, t8 = t4 * t4;
    return t8 * tt;
}

// ======== GEMM1: MX-fp8 e4m3, 128x128 tile, BK=128, 16x16x128 scaled MFMA ========
// (R14 proven: ~60 us.) Grid MUST be 2048 = 8 xcd * 32 cu * 8 rnd (banded map).
__global__ __launch_bounds__(256, 3) void gemm1f_kernel(
    const unsigned char* __restrict__ Ap, const unsigned char* __restrict__ Bp,
    ushort* __restrict__ Cp, int N, int K) {
    __shared__ unsigned char la[128 * 128] __attribute__((aligned(16)));
    __shared__ unsigned char lb[128 * 128] __attribute__((aligned(16)));
    const int tid = threadIdx.x;
    const int w = tid >> 6, lane = tid & 63;
    const int bid = blockIdx.x;
    const int xcd = bid & 7, cu = (bid >> 3) & 31, rnd = bid >> 8;
    const int brow = (xcd * 8 + (cu >> 2)) * 128;
    const int bcol = (rnd * 4 + (cu & 3)) * 128;
    const int wr = (w >> 1) * 64;
    const int wc = (w & 1) * 64;
    f32x4 acc[4][4] = {};
    const int srow = lane >> 3;
    const int scolb = ((lane & 7) ^ (lane >> 3)) << 4;

    for (int k0 = 0; k0 < K; k0 += 128) {
#pragma unroll
        for (int it = 0; it < 4; ++it) {
            const int rb = w * 32 + it * 8;
            const unsigned char* ga = Ap + (size_t)(brow + rb + srow) * K + k0 + scolb;
            const unsigned char* gb = Bp + (size_t)(bcol + rb + srow) * K + k0 + scolb;
            __builtin_amdgcn_global_load_lds(
                (const __attribute__((address_space(1))) void*)ga,
                (__attribute__((address_space(3))) void*)&la[rb * 128], 16, 0, 0);
            __builtin_amdgcn_global_load_lds(
                (const __attribute__((address_space(1))) void*)gb,
                (__attribute__((address_space(3))) void*)&lb[rb * 128], 16, 0, 0);
        }
        __syncthreads();
        i32x8 af[4], bfr[4];
        const int base = (lane >> 4) << 5;
#pragma unroll
        for (int m = 0; m < 4; ++m) {
            const int row = wr + m * 16 + (lane & 15);
            const int key = (row & 7) << 4;
            const uint4 lo = *(const uint4*)(la + row * 128 + (base ^ key));
            const uint4 hi = *(const uint4*)(la + row * 128 + ((base + 16) ^ key));
            af[m] = (i32x8){(int)lo.x, (int)lo.y, (int)lo.z, (int)lo.w,
                            (int)hi.x, (int)hi.y, (int)hi.z, (int)hi.w};
        }
#pragma unroll
        for (int n = 0; n < 4; ++n) {
            const int row = wc + n * 16 + (lane & 15);
            const int key = (row & 7) << 4;
            const uint4 lo = *(const uint4*)(lb + row * 128 + (base ^ key));
            const uint4 hi = *(const uint4*)(lb + row * 128 + ((base + 16) ^ key));
            bfr[n] = (i32x8){(int)lo.x, (int)lo.y, (int)lo.z, (int)lo.w,
                             (int)hi.x, (int)hi.y, (int)hi.z, (int)hi.w};
        }
#pragma unroll
        for (int m = 0; m < 4; ++m)
#pragma unroll
            for (int n = 0; n < 4; ++n)
                acc[m][n] = __builtin_amdgcn_mfma_scale_f32_16x16x128_f8f6f4(
                    af[m], bfr[n], acc[m][n], 0, 0,
                    0, 0x7F7F7F7F, 0, 0x7F7F7F7F);
        __syncthreads();
    }
    const int crow0 = brow + wr + ((lane >> 4) << 2);
    const int ccol0 = bcol + wc + (lane & 15);
#pragma unroll
    for (int m = 0; m < 4; ++m)
#pragma unroll
        for (int n = 0; n < 4; ++n)
#pragma unroll
            for (int r = 0; r < 4; ++r) {
                int row = crow0 + m * 16 + r;
                int col = ccol0 + n * 16;
                Cp[(size_t)row * N + col] =
                    f2bf(yoso_act(acc[m][n][r] * 0.00390625f));
            }
}

// ======== GEMM2: 256x128 tile, BK=128, single-buf 96K LDS, 2 barriers/step ========
// R10-style fat-step structure (R15 post-mortem: the 8-phase loop's 512 barrier
// crossings were ~2/3 of GEMM2's cycles; this has 64).  8 waves 4m x 2n (wave tile
// 64x64, acc[4][4]); 256-B LDS rows, 16-slot XOR swizzle slot^=(row&15) — inverse
// pre-applied on the global source (rule 21), conflict-free on both sides.
// Direct f32 stores from acc. Grid MUST be 256 = 8 xcd * 32 cu (banded map).
__global__ __launch_bounds__(512) void gemm2k_kernel(
    const ushort* __restrict__ Ap, const ushort* __restrict__ Bp,
    float* __restrict__ Cv, int N, int K, int nt) {
    __shared__ char lds[98304] __attribute__((aligned(16)));
    const int tid = threadIdx.x;
    const int w = tid >> 6, lane = tid & 63;
    const int wm = w >> 1, wn = w & 1;       // 4m x 2n wave grid
    const int bid = blockIdx.x;
    const int xcd = bid & 7, cu = bid >> 3;
    const int brow = (xcd * 4 + (cu >> 3)) * 256;
    const int bcol = (cu & 7) * 128;
    // staging: unit u = 4 KiB = 16 rows x 256 B; thread covers row u*16+(tid>>4),
    // slot tid&15. Source slot pre-swizzled: (tid&15) ^ (row&15) = (tid&15)^(tid>>4&15).
    const int strow = tid >> 4;              // row within unit (0..15... for 512 threads: 0..31)
    // NOTE: 512 threads -> unit = 8 KiB = 32 rows; slot key uses row&15 = strow&15.
    const int sslot = (tid & 15) ^ (strow & 15);
    const int scolb = sslot << 4;            // byte offset of pre-swizzled 16B chunk

    f32x4 acc[4][4] = {};

    auto stage = [&](int t) {
        // A: 64 KiB = 8 units x 8 KiB (32 rows each)
#pragma unroll
        for (int u = 0; u < 8; ++u) {
            int grow = brow + u * 32 + strow;
            const char* src = (const char*)Ap + ((size_t)grow * K + t * 128) * 2 + scolb;
            __builtin_amdgcn_global_load_lds(
                (const __attribute__((address_space(1))) void*)src,
                (__attribute__((address_space(3))) void*)&lds[u * 8192 + tid * 16], 16, 0, 0);
        }
        // B: 32 KiB = 4 units
#pragma unroll
        for (int u = 0; u < 4; ++u) {
            int grow = bcol + u * 32 + strow;
            const char* src = (const char*)Bp + ((size_t)grow * K + t * 128) * 2 + scolb;
            __builtin_amdgcn_global_load_lds(
                (const __attribute__((address_space(1))) void*)src,
                (__attribute__((address_space(3))) void*)&lds[65536 + u * 8192 + tid * 16],
                16, 0, 0);
        }
    };

    for (int t = 0; t < nt; ++t) {
        stage(t);
        __syncthreads();   // drains vmcnt(0) + barrier
#pragma unroll
        for (int ks = 0; ks < 4; ++ks) {
            bf16x8 af[4], bfr[4];
            const int ckey = lane & 15;     // == row&15 for all frag rows
            const int chunk = ks * 4 + (lane >> 4);
#pragma unroll
            for (int m = 0; m < 4; ++m) {
                int row = wm * 64 + m * 16 + (lane & 15);
                af[m] = *(const bf16x8*)(lds + row * 256 + ((chunk ^ ckey) << 4));
            }
#pragma unroll
            for (int n = 0; n < 4; ++n) {
                int row = wn * 64 + n * 16 + (lane & 15);
                bfr[n] = *(const bf16x8*)(lds + 65536 + row * 256 + ((chunk ^ ckey) << 4));
            }
#pragma unroll
            for (int m = 0; m < 4; ++m)
#pragma unroll
                for (int n = 0; n < 4; ++n)
                    acc[m][n] = __builtin_amdgcn_mfma_f32_16x16x32_bf16(
                        af[m], bfr[n], acc[m][n], 0, 0, 0);
        }
        __syncthreads();   // protect LDS before next-step overwrite
    }

    // direct f32 stores: 16-lane groups write 64-B contiguous segments
    const int crow0 = brow + wm * 64 + ((lane >> 4) << 2);
    const int ccol0 = bcol + wn * 64 + (lane & 15);
#pragma unroll
    for (int m = 0; m < 4; ++m)
#pragma unroll
        for (int n = 0; n < 4; ++n)
#pragma unroll
            for (int r = 0; r < 4; ++r) {
                int row = crow0 + m * 16 + r;
                int col = ccol0 + n * 16;
                Cv[(size_t)row * N + col] = acc[m][n][r];
            }
}

// ---------------- Merged prep: LN+qnorm -> fp8 | knorm -> fp8 | q_weight transpose -> bf16 ----------------
__global__ __launch_bounds__(256) void prep_kernel(
    const float* __restrict__ hs, const float* __restrict__ lnw,
    const float* __restrict__ lnb, const float* __restrict__ kw,
    const float* __restrict__ qw, unsigned char* __restrict__ Qf,
    unsigned char* __restrict__ Kf, ushort* __restrict__ VT) {
    __shared__ float smem[64][65];
    const int b = blockIdx.x, t = threadIdx.x;
    const int lane = t & 63, wid = t >> 6;
    if (b < NR) {
        const float4 v = reinterpret_cast<const float4*>(hs + (size_t)b * HD)[t];
        float s  = v.x + v.y + v.z + v.w;
        float ss = v.x*v.x + v.y*v.y + v.z*v.z + v.w*v.w;
        s = wave_sum(s); ss = wave_sum(ss);
        if (lane == 0) { smem[0][wid] = s; smem[1][wid] = ss; }
        __syncthreads();
        float st  = smem[0][0] + smem[0][1] + smem[0][2] + smem[0][3];
        float sst = smem[1][0] + smem[1][1] + smem[1][2] + smem[1][3];
        float mu   = st * (1.0f / HD);
        float var  = sst * (1.0f / HD) - mu * mu;
        float rstd = rsqrtf(var + 1e-12f);
        const float4 wv = reinterpret_cast<const float4*>(lnw)[t];
        const float4 bv = reinterpret_cast<const float4*>(lnb)[t];
        float y0 = (v.x - mu) * rstd * wv.x + bv.x;
        float y1 = (v.y - mu) * rstd * wv.y + bv.y;
        float y2 = (v.z - mu) * rstd * wv.z + bv.z;
        float y3 = (v.w - mu) * rstd * wv.w + bv.w;
        float n2 = wave_sum(y0*y0 + y1*y1 + y2*y2 + y3*y3);
        if (lane == 0) smem[2][wid] = n2;
        __syncthreads();
        float nt2 = smem[2][0] + smem[2][1] + smem[2][2] + smem[2][3];
        float sc = 16.0f / fmaxf(sqrtf(nt2), 1e-12f);   // x16 prescale for fp8
        int r = __builtin_amdgcn_cvt_pk_fp8_f32(y0 * sc, y1 * sc, 0, false);
        r = __builtin_amdgcn_cvt_pk_fp8_f32(y2 * sc, y3 * sc, r, true);
        reinterpret_cast<int*>(Qf + (size_t)b * HD)[t] = r;
    } else if (b < NR + ID) {
        const int row = b - NR;
        const float4 v = reinterpret_cast<const float4*>(kw + (size_t)row * HD)[t];
        float n2 = wave_sum(v.x*v.x + v.y*v.y + v.z*v.z + v.w*v.w);
        if (lane == 0) smem[0][wid] = n2;
        __syncthreads();
        float nt2 = smem[0][0] + smem[0][1] + smem[0][2] + smem[0][3];
        float sc = 16.0f / fmaxf(sqrtf(nt2), 1e-12f);   // x16 prescale for fp8
        int r = __builtin_amdgcn_cvt_pk_fp8_f32(v.x * sc, v.y * sc, 0, false);
        r = __builtin_amdgcn_cvt_pk_fp8_f32(v.z * sc, v.w * sc, r, true);
        reinterpret_cast<int*>(Kf + (size_t)row * HD)[t] = r;
    } else {
        const int b2 = b - NR - ID;
        const int bi = (b2 & 63) * 64, bh = (b2 >> 6) * 64;
        const int r0 = t >> 4, c0 = (t & 15) << 2;
#pragma unroll
        for (int rr = 0; rr < 64; rr += 16) {
            float4 val = *reinterpret_cast<const float4*>(
                &qw[(size_t)(bi + rr + r0) * HD + bh + c0]);
            smem[rr + r0][c0 + 0] = val.x; smem[rr + r0][c0 + 1] = val.y;
            smem[rr + r0][c0 + 2] = val.z; smem[rr + r0][c0 + 3] = val.w;
        }
        __syncthreads();
#pragma unroll
        for (int rr = 0; rr < 64; rr += 16) {
            ushort4 o;
            o.x = f2bf(smem[c0 + 0][rr + r0]);
            o.y = f2bf(smem[c0 + 1][rr + r0]);
            o.z = f2bf(smem[c0 + 2][rr + r0]);
            o.w = f2bf(smem[c0 + 3][rr + r0]);
            *reinterpret_cast<ushort4*>(&VT[(size_t)(bh + rr + r0) * ID + bi + c0]) = o;
        }
    }
}

// ---------------- in-place row l2-normalize + bias ----------------
__global__ __launch_bounds__(256) void outnorm_kernel(
    float* __restrict__ X, const float* __restrict__ bias) {
    __shared__ float red2[4];
    const int row = blockIdx.x, t = threadIdx.x;
    const int lane = t & 63, wid = t >> 6;
    float4 v = reinterpret_cast<float4*>(X + (size_t)row * HD)[t];
    float n2 = wave_sum(v.x*v.x + v.y*v.y + v.z*v.z + v.w*v.w);
    if (lane == 0) red2[wid] = n2;
    __syncthreads();
    float nt = red2[0] + red2[1] + red2[2] + red2[3];
    float sc = 1.0f / fmaxf(sqrtf(nt), 1e-12f);
    const float4 bv = reinterpret_cast<const float4*>(bias)[t];
    float4 o;
    o.x = v.x * sc + bv.x; o.y = v.y * sc + bv.y;
    o.z = v.z * sc + bv.z; o.w = v.w * sc + bv.w;
    reinterpret_cast<float4*>(X + (size_t)row * HD)[t] = o;
}

extern "C" void kernel_launch(void* const* d_in, const int* in_sizes, int n_in,
                              void* d_out, int out_size, void* d_ws, size_t ws_size,
                              hipStream_t stream) {
    const float* hs   = (const float*)d_in[0];  // hidden_states [4,2048,1024]
    const float* lnw  = (const float*)d_in[1];  // ln_weight [1024]
    const float* lnb  = (const float*)d_in[2];  // ln_bias [1024]
    const float* kw   = (const float*)d_in[3];  // k_weight [4096,1024]
    const float* qw   = (const float*)d_in[4];  // q_weight [4096,1024]
    const float* bias = (const float*)d_in[5];  // bias [1024]
    float* out = (float*)d_out;

    char* ws = (char*)d_ws;
    unsigned char* Qf = (unsigned char*)(ws);                       //  8 MiB fp8
    unsigned char* Kf = (unsigned char*)(ws + (size_t)8388608);     //  4 MiB fp8
    ushort* VT   = (ushort*)(ws + (size_t)12582912);                //  8 MiB bf16
    ushort* Bmat = (ushort*)(ws + (size_t)20971520);                // 64 MiB bf16

    // merged prep: 8192 LN rows (fp8) + 4096 K rows (fp8) + 1024 transpose tiles (bf16)
    prep_kernel<<<NR + ID + 1024, 256, 0, stream>>>(hs, lnw, lnb, kw, qw, Qf, Kf, VT);
    // GEMM1: MX-fp8 [8192,1024] x [4096,1024]^T -> act -> Bmat bf16 [8192,4096]
    gemm1f_kernel<<<(NR / 128) * (ID / 128), 256, 0, stream>>>(
        Qf, Kf, Bmat, ID, HD);
    // GEMM2: [8192,4096] x [1024,4096]^T -> out f32 [8192,1024]
    //        fat-step 2-barrier structure, BK=128; grid 256 = 8 xcd * 32 cu
    gemm2k_kernel<<<(NR / 256) * (HD / 128), 512, 0, stream>>>(
        Bmat, VT, out, HD, ID, ID / 128);
    outnorm_kernel<<<NR, 256, 0, stream>>>(out, bias);
}

// Round 17
// 154.057 us; speedup vs baseline: 1.0856x; 1.0856x over previous
//
#include <hip/hip_runtime.h>

#define HD 1024
#define ID 4096
#define NR 8192

typedef float f32x4 __attribute__((ext_vector_type(4)));
typedef __bf16 bf16x8 __attribute__((ext_vector_type(8)));
typedef int i32x8 __attribute__((ext_vector_type(8)));

__device__ inline ushort f2bf(float f) {
    union { float f; unsigned u; } v; v.f = f;
    unsigned u = v.u;
    unsigned r = (u + 0x7fffu + ((u >> 16) & 1u)) >> 16;  // RNE
    return (ushort)r;
}

__device__ inline float wave_sum(float v) {
#pragma unroll
    for (int o = 32; o > 0; o >>= 1) v += __shfl_xor(v, o, 64);
    return v;
}

// YOSO activation: t = 1 - acos(s)/pi via A&S 4.4.45 (|err| <= 6.7e-5 rad), out t^9.
__device__ __forceinline__ float yoso_act(float v) {
    float s = fminf(fmaxf(v, -0.999999f), 0.999999f);
    float a = fabsf(s);
    float p = 0.49998557f + a * (-0.06751706f + a * (0.02363794f - a * 0.00596170f));
    float q = sqrtf(1.0f - a) * p;           // acos(|s|)/pi
    float tt = (s >= 0.0f) ? 1.0f - q : q;
    float t2 = tt * tt, t4 = t2 * t2, t8 = t4 * t4;
    return t8 * tt;
}

// ======== GEMM1: MX-fp8 e4m3, 128x128 tile, BK=128, 16x16x128 scaled MFMA ========
// (R14 proven: ~60 us.) Grid MUST be 2048 = 8 xcd * 32 cu * 8 rnd (banded map).
__global__ __launch_bounds__(256, 3) void gemm1f_kernel(
    const unsigned char* __restrict__ Ap, const unsigned char* __restrict__ Bp,
    ushort* __restrict__ Cp, int N, int K) {
    __shared__ unsigned char la[128 * 128] __attribute__((aligned(16)));
    __shared__ unsigned char lb[128 * 128] __attribute__((aligned(16)));
    const int tid = threadIdx.x;
    const int w = tid >> 6, lane = tid & 63;
    const int bid = blockIdx.x;
    const int xcd = bid & 7, cu = (bid >> 3) & 31, rnd = bid >> 8;
    const int brow = (xcd * 8 + (cu >> 2)) * 128;
    const int bcol = (rnd * 4 + (cu & 3)) * 128;
    const int wr = (w >> 1) * 64;
    const int wc = (w & 1) * 64;
    f32x4 acc[4][4] = {};
    const int srow = lane >> 3;
    const int scolb = ((lane & 7) ^ (lane >> 3)) << 4;

    for (int k0 = 0; k0 < K; k0 += 128) {
#pragma unroll
        for (int it = 0; it < 4; ++it) {
            const int rb = w * 32 + it * 8;
            const unsigned char* ga = Ap + (size_t)(brow + rb + srow) * K + k0 + scolb;
            const unsigned char* gb = Bp + (size_t)(bcol + rb + srow) * K + k0 + scolb;
            __builtin_amdgcn_global_load_lds(
                (const __attribute__((address_space(1))) void*)ga,
                (__attribute__((address_space(3))) void*)&la[rb * 128], 16, 0, 0);
            __builtin_amdgcn_global_load_lds(
                (const __attribute__((address_space(1))) void*)gb,
                (__attribute__((address_space(3))) void*)&lb[rb * 128], 16, 0, 0);
        }
        __syncthreads();
        i32x8 af[4], bfr[4];
        const int base = (lane >> 4) << 5;
#pragma unroll
        for (int m = 0; m < 4; ++m) {
            const int row = wr + m * 16 + (lane & 15);
            const int key = (row & 7) << 4;
            const uint4 lo = *(const uint4*)(la + row * 128 + (base ^ key));
            const uint4 hi = *(const uint4*)(la + row * 128 + ((base + 16) ^ key));
            af[m] = (i32x8){(int)lo.x, (int)lo.y, (int)lo.z, (int)lo.w,
                            (int)hi.x, (int)hi.y, (int)hi.z, (int)hi.w};
        }
#pragma unroll
        for (int n = 0; n < 4; ++n) {
            const int row = wc + n * 16 + (lane & 15);
            const int key = (row & 7) << 4;
            const uint4 lo = *(const uint4*)(lb + row * 128 + (base ^ key));
            const uint4 hi = *(const uint4*)(lb + row * 128 + ((base + 16) ^ key));
            bfr[n] = (i32x8){(int)lo.x, (int)lo.y, (int)lo.z, (int)lo.w,
                             (int)hi.x, (int)hi.y, (int)hi.z, (int)hi.w};
        }
#pragma unroll
        for (int m = 0; m < 4; ++m)
#pragma unroll
            for (int n = 0; n < 4; ++n)
                acc[m][n] = __builtin_amdgcn_mfma_scale_f32_16x16x128_f8f6f4(
                    af[m], bfr[n], acc[m][n], 0, 0,
                    0, 0x7F7F7F7F, 0, 0x7F7F7F7F);
        __syncthreads();
    }
    const int crow0 = brow + wr + ((lane >> 4) << 2);
    const int ccol0 = bcol + wc + (lane & 15);
#pragma unroll
    for (int m = 0; m < 4; ++m)
#pragma unroll
        for (int n = 0; n < 4; ++n)
#pragma unroll
            for (int r = 0; r < 4; ++r) {
                int row = crow0 + m * 16 + r;
                int col = ccol0 + n * 16;
                Cp[(size_t)row * N + col] =
                    f2bf(yoso_act(acc[m][n][r] * 0.00390625f));
            }
}

// ======== GEMM2: 256x128 tile, BK=64 DOUBLE-BUFFERED (96K LDS), 8 waves, 1 blk/CU ========
// R16 post-mortem: single-buf exposes a ~2000-cy staging stall per step (vmcnt(0)
// drain with MFMA+LDS-read pipes idle). Here stage(t+1) is issued BEFORE compute(t):
// staging writes drain through the LDS port interleaved with frag reads; one
// vmcnt(0)+barrier per step. LDS rows 128 B, 8-slot XOR swizzle key (row&7)
// (inverse pre-applied on global source, rule 21). Direct f32 stores.
// Grid MUST be 256 = 8 xcd * 32 cu (banded map).
__global__ __launch_bounds__(512) void gemm2d_kernel(
    const ushort* __restrict__ Ap, const ushort* __restrict__ Bp,
    float* __restrict__ Cv, int N, int K, int nt) {
    __shared__ char lds[98304] __attribute__((aligned(16)));
    const int tid = threadIdx.x;
    const int w = tid >> 6, lane = tid & 63;
    const int wm = w >> 1, wn = w & 1;       // 4m x 2n wave grid, wave tile 64x64
    const int bid = blockIdx.x;
    const int xcd = bid & 7, cu = bid >> 3;
    const int brow = (xcd * 4 + (cu >> 3)) * 256;
    const int bcol = (cu & 7) * 128;
    const int srow = lane >> 3;                          // 0..7
    const int scolb = ((lane & 7) ^ (lane >> 3)) << 4;   // pre-swizzled source slot

    f32x4 acc[4][4] = {};

    // stage one BK=64 slice into buffer db: A 32K (4 units), B 16K (2 units);
    // wave w covers rows u*64 + w*8 + srow of each unit.
    auto stage = [&](int t, int db) {
#pragma unroll
        for (int u = 0; u < 4; ++u) {
            int grow = brow + u * 64 + w * 8 + srow;
            const char* src = (const char*)Ap + ((size_t)grow * K + t * 64) * 2 + scolb;
            __builtin_amdgcn_global_load_lds(
                (const __attribute__((address_space(1))) void*)src,
                (__attribute__((address_space(3))) void*)&lds[db * 32768 + u * 8192 + w * 1024],
                16, 0, 0);
        }
#pragma unroll
        for (int u = 0; u < 2; ++u) {
            int grow = bcol + u * 64 + w * 8 + srow;
            const char* src = (const char*)Bp + ((size_t)grow * K + t * 64) * 2 + scolb;
            __builtin_amdgcn_global_load_lds(
                (const __attribute__((address_space(1))) void*)src,
                (__attribute__((address_space(3))) void*)&lds[65536 + db * 16384 + u * 8192 + w * 1024],
                16, 0, 0);
        }
    };

    stage(0, 0);
    asm volatile("s_waitcnt vmcnt(0)" ::: "memory");
    __builtin_amdgcn_s_barrier();

    for (int t = 0; t < nt; ++t) {
        const int db = t & 1;
        const bool more = (t + 1 < nt);
        if (more) stage(t + 1, db ^ 1);   // issue FIRST: drains under compute(t)
#pragma unroll
        for (int ks = 0; ks < 2; ++ks) {
            bf16x8 af[4], bfr[4];
            const int chunk = ks * 4 + (lane >> 4);      // 0..7
#pragma unroll
            for (int m = 0; m < 4; ++m) {
                int row = wm * 64 + m * 16 + (lane & 15);
                af[m] = *(const bf16x8*)(lds + db * 32768 + row * 128 +
                                         ((chunk ^ (row & 7)) << 4));
            }
#pragma unroll
            for (int n = 0; n < 4; ++n) {
                int row = wn * 64 + n * 16 + (lane & 15);
                bfr[n] = *(const bf16x8*)(lds + 65536 + db * 16384 + row * 128 +
                                          ((chunk ^ (row & 7)) << 4));
            }
#pragma unroll
            for (int m = 0; m < 4; ++m)
#pragma unroll
                for (int n = 0; n < 4; ++n)
                    acc[m][n] = __builtin_amdgcn_mfma_f32_16x16x32_bf16(
                        af[m], bfr[n], acc[m][n], 0, 0, 0);
        }
        if (more) {
            __builtin_amdgcn_sched_barrier(0);
            asm volatile("s_waitcnt vmcnt(0)" ::: "memory");  // stage(t+1) landed
            __builtin_amdgcn_s_barrier();                     // safe to overwrite buf db
        }
    }

    // direct f32 stores: 16-lane groups write 64-B contiguous segments
    const int crow0 = brow + wm * 64 + ((lane >> 4) << 2);
    const int ccol0 = bcol + wn * 64 + (lane & 15);
#pragma unroll
    for (int m = 0; m < 4; ++m)
#pragma unroll
        for (int n = 0; n < 4; ++n)
#pragma unroll
            for (int r = 0; r < 4; ++r) {
                int row = crow0 + m * 16 + r;
                int col = ccol0 + n * 16;
                Cv[(size_t)row * N + col] = acc[m][n][r];
            }
}

// ---------------- Merged prep: LN+qnorm -> fp8 | knorm -> fp8 | q_weight transpose -> bf16 ----------------
__global__ __launch_bounds__(256) void prep_kernel(
    const float* __restrict__ hs, const float* __restrict__ lnw,
    const float* __restrict__ lnb, const float* __restrict__ kw,
    const float* __restrict__ qw, unsigned char* __restrict__ Qf,
    unsigned char* __restrict__ Kf, ushort* __restrict__ VT) {
    __shared__ float smem[64][65];
    const int b = blockIdx.x, t = threadIdx.x;
    const int lane = t & 63, wid = t >> 6;
    if (b < NR) {
        const float4 v = reinterpret_cast<const float4*>(hs + (size_t)b * HD)[t];
        float s  = v.x + v.y + v.z + v.w;
        float ss = v.x*v.x + v.y*v.y + v.z*v.z + v.w*v.w;
        s = wave_sum(s); ss = wave_sum(ss);
        if (lane == 0) { smem[0][wid] = s; smem[1][wid] = ss; }
        __syncthreads();
        float st  = smem[0][0] + smem[0][1] + smem[0][2] + smem[0][3];
        float sst = smem[1][0] + smem[1][1] + smem[1][2] + smem[1][3];
        float mu   = st * (1.0f / HD);
        float var  = sst * (1.0f / HD) - mu * mu;
        float rstd = rsqrtf(var + 1e-12f);
        const float4 wv = reinterpret_cast<const float4*>(lnw)[t];
        const float4 bv = reinterpret_cast<const float4*>(lnb)[t];
        float y0 = (v.x - mu) * rstd * wv.x + bv.x;
        float y1 = (v.y - mu) * rstd * wv.y + bv.y;
        float y2 = (v.z - mu) * rstd * wv.z + bv.z;
        float y3 = (v.w - mu) * rstd * wv.w + bv.w;
        float n2 = wave_sum(y0*y0 + y1*y1 + y2*y2 + y3*y3);
        if (lane == 0) smem[2][wid] = n2;
        __syncthreads();
        float nt2 = smem[2][0] + smem[2][1] + smem[2][2] + smem[2][3];
        float sc = 16.0f / fmaxf(sqrtf(nt2), 1e-12f);   // x16 prescale for fp8
        int r = __builtin_amdgcn_cvt_pk_fp8_f32(y0 * sc, y1 * sc, 0, false);
        r = __builtin_amdgcn_cvt_pk_fp8_f32(y2 * sc, y3 * sc, r, true);
        reinterpret_cast<int*>(Qf + (size_t)b * HD)[t] = r;
    } else if (b < NR + ID) {
        const int row = b - NR;
        const float4 v = reinterpret_cast<const float4*>(kw + (size_t)row * HD)[t];
        float n2 = wave_sum(v.x*v.x + v.y*v.y + v.z*v.z + v.w*v.w);
        if (lane == 0) smem[0][wid] = n2;
        __syncthreads();
        float nt2 = smem[0][0] + smem[0][1] + smem[0][2] + smem[0][3];
        float sc = 16.0f / fmaxf(sqrtf(nt2), 1e-12f);   // x16 prescale for fp8
        int r = __builtin_amdgcn_cvt_pk_fp8_f32(v.x * sc, v.y * sc, 0, false);
        r = __builtin_amdgcn_cvt_pk_fp8_f32(v.z * sc, v.w * sc, r, true);
        reinterpret_cast<int*>(Kf + (size_t)row * HD)[t] = r;
    } else {
        const int b2 = b - NR - ID;
        const int bi = (b2 & 63) * 64, bh = (b2 >> 6) * 64;
        const int r0 = t >> 4, c0 = (t & 15) << 2;
#pragma unroll
        for (int rr = 0; rr < 64; rr += 16) {
            float4 val = *reinterpret_cast<const float4*>(
                &qw[(size_t)(bi + rr + r0) * HD + bh + c0]);
            smem[rr + r0][c0 + 0] = val.x; smem[rr + r0][c0 + 1] = val.y;
            smem[rr + r0][c0 + 2] = val.z; smem[rr + r0][c0 + 3] = val.w;
        }
        __syncthreads();
#pragma unroll
        for (int rr = 0; rr < 64; rr += 16) {
            ushort4 o;
            o.x = f2bf(smem[c0 + 0][rr + r0]);
            o.y = f2bf(smem[c0 + 1][rr + r0]);
            o.z = f2bf(smem[c0 + 2][rr + r0]);
            o.w = f2bf(smem[c0 + 3][rr + r0]);
            *reinterpret_cast<ushort4*>(&VT[(size_t)(bh + rr + r0) * ID + bi + c0]) = o;
        }
    }
}

// ---------------- in-place row l2-normalize + bias ----------------
__global__ __launch_bounds__(256) void outnorm_kernel(
    float* __restrict__ X, const float* __restrict__ bias) {
    __shared__ float red2[4];
    const int row = blockIdx.x, t = threadIdx.x;
    const int lane = t & 63, wid = t >> 6;
    float4 v = reinterpret_cast<float4*>(X + (size_t)row * HD)[t];
    float n2 = wave_sum(v.x*v.x + v.y*v.y + v.z*v.z + v.w*v.w);
    if (lane == 0) red2[wid] = n2;
    __syncthreads();
    float nt = red2[0] + red2[1] + red2[2] + red2[3];
    float sc = 1.0f / fmaxf(sqrtf(nt), 1e-12f);
    const float4 bv = reinterpret_cast<const float4*>(bias)[t];
    float4 o;
    o.x = v.x * sc + bv.x; o.y = v.y * sc + bv.y;
    o.z = v.z * sc + bv.z; o.w = v.w * sc + bv.w;
    reinterpret_cast<float4*>(X + (size_t)row * HD)[t] = o;
}

extern "C" void kernel_launch(void* const* d_in, const int* in_sizes, int n_in,
                              void* d_out, int out_size, void* d_ws, size_t ws_size,
                              hipStream_t stream) {
    const float* hs   = (const float*)d_in[0];  // hidden_states [4,2048,1024]
    const float* lnw  = (const float*)d_in[1];  // ln_weight [1024]
    const float* lnb  = (const float*)d_in[2];  // ln_bias [1024]
    const float* kw   = (const float*)d_in[3];  // k_weight [4096,1024]
    const float* qw   = (const float*)d_in[4];  // q_weight [4096,1024]
    const float* bias = (const float*)d_in[5];  // bias [1024]
    float* out = (float*)d_out;

    char* ws = (char*)d_ws;
    unsigned char* Qf = (unsigned char*)(ws);                       //  8 MiB fp8
    unsigned char* Kf = (unsigned char*)(ws + (size_t)8388608);     //  4 MiB fp8
    ushort* VT   = (ushort*)(ws + (size_t)12582912);                //  8 MiB bf16
    ushort* Bmat = (ushort*)(ws + (size_t)20971520);                // 64 MiB bf16

    // merged prep: 8192 LN rows (fp8) + 4096 K rows (fp8) + 1024 transpose tiles (bf16)
    prep_kernel<<<NR + ID + 1024, 256, 0, stream>>>(hs, lnw, lnb, kw, qw, Qf, Kf, VT);
    // GEMM1: MX-fp8 [8192,1024] x [4096,1024]^T -> act -> Bmat bf16 [8192,4096]
    gemm1f_kernel<<<(NR / 128) * (ID / 128), 256, 0, stream>>>(
        Qf, Kf, Bmat, ID, HD);
    // GEMM2: [8192,4096] x [1024,4096]^T -> out f32 [8192,1024]
    //        BK=64 double-buffered issue-early; grid 256 = 8 xcd * 32 cu
    gemm2d_kernel<<<(NR / 256) * (HD / 128), 512, 0, stream>>>(
        Bmat, VT, out, HD, ID, ID / 64);
    outnorm_kernel<<<NR, 256, 0, stream>>>(out, bias);
}

// Round 18
// 153.346 us; speedup vs baseline: 1.0906x; 1.0046x over previous
//
#include <hip/hip_runtime.h>

#define HD 1024
#define ID 4096
#define NR 8192

typedef float f32x4 __attribute__((ext_vector_type(4)));
typedef __bf16 bf16x8 __attribute__((ext_vector_type(8)));
typedef int i32x8 __attribute__((ext_vector_type(8)));

__device__ inline ushort f2bf(float f) {
    union { float f; unsigned u; } v; v.f = f;
    unsigned u = v.u;
    unsigned r = (u + 0x7fffu + ((u >> 16) & 1u)) >> 16;  // RNE
    return (ushort)r;
}

__device__ inline float wave_sum(float v) {
#pragma unroll
    for (int o = 32; o > 0; o >>= 1) v += __shfl_xor(v, o, 64);
    return v;
}

// YOSO activation: t = 1 - acos(s)/pi via A&S 4.4.45 (|err| <= 6.7e-5 rad), out t^9.
__device__ __forceinline__ float yoso_act(float v) {
    float s = fminf(fmaxf(v, -0.999999f), 0.999999f);
    float a = fabsf(s);
    float p = 0.49998557f + a * (-0.06751706f + a * (0.02363794f - a * 0.00596170f));
    float q = sqrtf(1.0f - a) * p;           // acos(|s|)/pi
    float tt = (s >= 0.0f) ? 1.0f - q : q;
    float t2 = tt * tt, t4 = t2 * t2, t8 = t4 * t4;
    return t8 * tt;
}

// ======== GEMM1: MX-fp8 e4m3, 128x128 tile, BK=128, 16x16x128 scaled MFMA ========
// (R14 proven.) Grid MUST be 2048 = 8 xcd * 32 cu * 8 rnd (banded map).
__global__ __launch_bounds__(256, 3) void gemm1f_kernel(
    const unsigned char* __restrict__ Ap, const unsigned char* __restrict__ Bp,
    ushort* __restrict__ Cp, int N, int K) {
    __shared__ unsigned char la[128 * 128] __attribute__((aligned(16)));
    __shared__ unsigned char lb[128 * 128] __attribute__((aligned(16)));
    const int tid = threadIdx.x;
    const int w = tid >> 6, lane = tid & 63;
    const int bid = blockIdx.x;
    const int xcd = bid & 7, cu = (bid >> 3) & 31, rnd = bid >> 8;
    const int brow = (xcd * 8 + (cu >> 2)) * 128;
    const int bcol = (rnd * 4 + (cu & 3)) * 128;
    const int wr = (w >> 1) * 64;
    const int wc = (w & 1) * 64;
    f32x4 acc[4][4] = {};
    const int srow = lane >> 3;
    const int scolb = ((lane & 7) ^ (lane >> 3)) << 4;

    for (int k0 = 0; k0 < K; k0 += 128) {
#pragma unroll
        for (int it = 0; it < 4; ++it) {
            const int rb = w * 32 + it * 8;
            const unsigned char* ga = Ap + (size_t)(brow + rb + srow) * K + k0 + scolb;
            const unsigned char* gb = Bp + (size_t)(bcol + rb + srow) * K + k0 + scolb;
            __builtin_amdgcn_global_load_lds(
                (const __attribute__((address_space(1))) void*)ga,
                (__attribute__((address_space(3))) void*)&la[rb * 128], 16, 0, 0);
            __builtin_amdgcn_global_load_lds(
                (const __attribute__((address_space(1))) void*)gb,
                (__attribute__((address_space(3))) void*)&lb[rb * 128], 16, 0, 0);
        }
        __syncthreads();
        i32x8 af[4], bfr[4];
        const int base = (lane >> 4) << 5;
#pragma unroll
        for (int m = 0; m < 4; ++m) {
            const int row = wr + m * 16 + (lane & 15);
            const int key = (row & 7) << 4;
            const uint4 lo = *(const uint4*)(la + row * 128 + (base ^ key));
            const uint4 hi = *(const uint4*)(la + row * 128 + ((base + 16) ^ key));
            af[m] = (i32x8){(int)lo.x, (int)lo.y, (int)lo.z, (int)lo.w,
                            (int)hi.x, (int)hi.y, (int)hi.z, (int)hi.w};
        }
#pragma unroll
        for (int n = 0; n < 4; ++n) {
            const int row = wc + n * 16 + (lane & 15);
            const int key = (row & 7) << 4;
            const uint4 lo = *(const uint4*)(lb + row * 128 + (base ^ key));
            const uint4 hi = *(const uint4*)(lb + row * 128 + ((base + 16) ^ key));
            bfr[n] = (i32x8){(int)lo.x, (int)lo.y, (int)lo.z, (int)lo.w,
                             (int)hi.x, (int)hi.y, (int)hi.z, (int)hi.w};
        }
#pragma unroll
        for (int m = 0; m < 4; ++m)
#pragma unroll
            for (int n = 0; n < 4; ++n)
                acc[m][n] = __builtin_amdgcn_mfma_scale_f32_16x16x128_f8f6f4(
                    af[m], bfr[n], acc[m][n], 0, 0,
                    0, 0x7F7F7F7F, 0, 0x7F7F7F7F);
        __syncthreads();
    }
    const int crow0 = brow + wr + ((lane >> 4) << 2);
    const int ccol0 = bcol + wc + (lane & 15);
#pragma unroll
    for (int m = 0; m < 4; ++m)
#pragma unroll
        for (int n = 0; n < 4; ++n)
#pragma unroll
            for (int r = 0; r < 4; ++r) {
                int row = crow0 + m * 16 + r;
                int col = ccol0 + n * 16;
                Cp[(size_t)row * N + col] =
                    f2bf(yoso_act(acc[m][n][r] * 0.00390625f));
            }
}

// ======== GEMM2: 256x128 tile, BK=64, TRIPLE-BUFFERED counted-vmcnt (144K LDS) ========
// Per step: vmcnt(6) [waits loads issued TWO compute-phases ago -> near-free] ->
// ONE raw s_barrier [all waves' own vmcnt passed => buf t fully landed cross-wave;
// all waves done with compute(t-1) => buf (t+2)%3 safe to overwrite] ->
// issue stage(t+2) -> compute(t).  LDS rows 128 B, 8-slot XOR swizzle key (row&7)
// (inverse pre-applied on global source, rule 21). Direct f32 stores.
// Grid MUST be 256 = 8 xcd * 32 cu (banded map). 8 waves 4m x 2n, wave tile 64x64.
__global__ __launch_bounds__(512) void gemm2t_kernel(
    const ushort* __restrict__ Ap, const ushort* __restrict__ Bp,
    float* __restrict__ Cv, int N, int K, int nt) {
    __shared__ char lds[147456] __attribute__((aligned(16)));  // A 3x32K @0, B 3x16K @98304
    const int tid = threadIdx.x;
    const int w = tid >> 6, lane = tid & 63;
    const int wm = w >> 1, wn = w & 1;
    const int bid = blockIdx.x;
    const int xcd = bid & 7, cu = bid >> 3;
    const int brow = (xcd * 4 + (cu >> 3)) * 256;
    const int bcol = (cu & 7) * 128;
    const int srow = lane >> 3;
    const int scolb = ((lane & 7) ^ (lane >> 3)) << 4;   // pre-swizzled source slot

    f32x4 acc[4][4] = {};

    // stage one BK=64 slice into buffer b: A 32K (4 units x 64 rows), B 16K (2 units)
    auto stage = [&](int t, int b) {
#pragma unroll
        for (int u = 0; u < 4; ++u) {
            int grow = brow + u * 64 + w * 8 + srow;
            const char* src = (const char*)Ap + ((size_t)grow * K + t * 64) * 2 + scolb;
            __builtin_amdgcn_global_load_lds(
                (const __attribute__((address_space(1))) void*)src,
                (__attribute__((address_space(3))) void*)&lds[b * 32768 + u * 8192 + w * 1024],
                16, 0, 0);
        }
#pragma unroll
        for (int u = 0; u < 2; ++u) {
            int grow = bcol + u * 64 + w * 8 + srow;
            const char* src = (const char*)Bp + ((size_t)grow * K + t * 64) * 2 + scolb;
            __builtin_amdgcn_global_load_lds(
                (const __attribute__((address_space(1))) void*)src,
                (__attribute__((address_space(3))) void*)&lds[98304 + b * 16384 + u * 8192 + w * 1024],
                16, 0, 0);
        }
    };

    // prologue: two stages in flight
    stage(0, 0);
    stage(1, 1);

    int bt = 0;  // buffer of step t
    for (int t = 0; t < nt; ++t) {
        const bool more2 = (t + 2 < nt);
        // wait: leave (t+1)'s 6 loads outstanding; (t)'s have landed.  Last step: drain.
        if (t + 1 < nt) asm volatile("s_waitcnt vmcnt(6)" ::: "memory");
        else            asm volatile("s_waitcnt vmcnt(0)" ::: "memory");
        __builtin_amdgcn_sched_barrier(0);
        __builtin_amdgcn_s_barrier();      // buf t landed cross-wave; buf (t+2)%3 free
        __builtin_amdgcn_sched_barrier(0);
        if (more2) {
            int b2 = bt + 2; if (b2 >= 3) b2 -= 3;
            stage(t + 2, b2);
        }
#pragma unroll
        for (int ks = 0; ks < 2; ++ks) {
            bf16x8 af[4], bfr[4];
            const int chunk = ks * 4 + (lane >> 4);      // 0..7
#pragma unroll
            for (int m = 0; m < 4; ++m) {
                int row = wm * 64 + m * 16 + (lane & 15);
                af[m] = *(const bf16x8*)(lds + bt * 32768 + row * 128 +
                                         ((chunk ^ (row & 7)) << 4));
            }
#pragma unroll
            for (int n = 0; n < 4; ++n) {
                int row = wn * 64 + n * 16 + (lane & 15);
                bfr[n] = *(const bf16x8*)(lds + 98304 + bt * 16384 + row * 128 +
                                          ((chunk ^ (row & 7)) << 4));
            }
#pragma unroll
            for (int m = 0; m < 4; ++m)
#pragma unroll
                for (int n = 0; n < 4; ++n)
                    acc[m][n] = __builtin_amdgcn_mfma_f32_16x16x32_bf16(
                        af[m], bfr[n], acc[m][n], 0, 0, 0);
        }
        ++bt; if (bt >= 3) bt -= 3;
    }

    // direct f32 stores: 16-lane groups write 64-B contiguous segments
    const int crow0 = brow + wm * 64 + ((lane >> 4) << 2);
    const int ccol0 = bcol + wn * 64 + (lane & 15);
#pragma unroll
    for (int m = 0; m < 4; ++m)
#pragma unroll
        for (int n = 0; n < 4; ++n)
#pragma unroll
            for (int r = 0; r < 4; ++r) {
                int row = crow0 + m * 16 + r;
                int col = ccol0 + n * 16;
                Cv[(size_t)row * N + col] = acc[m][n][r];
            }
}

// ---------------- Merged prep: LN+qnorm -> fp8 | knorm -> fp8 | q_weight transpose -> bf16 ----------------
__global__ __launch_bounds__(256) void prep_kernel(
    const float* __restrict__ hs, const float* __restrict__ lnw,
    const float* __restrict__ lnb, const float* __restrict__ kw,
    const float* __restrict__ qw, unsigned char* __restrict__ Qf,
    unsigned char* __restrict__ Kf, ushort* __restrict__ VT) {
    __shared__ float smem[64][65];
    const int b = blockIdx.x, t = threadIdx.x;
    const int lane = t & 63, wid = t >> 6;
    if (b < NR) {
        const float4 v = reinterpret_cast<const float4*>(hs + (size_t)b * HD)[t];
        float s  = v.x + v.y + v.z + v.w;
        float ss = v.x*v.x + v.y*v.y + v.z*v.z + v.w*v.w;
        s = wave_sum(s); ss = wave_sum(ss);
        if (lane == 0) { smem[0][wid] = s; smem[1][wid] = ss; }
        __syncthreads();
        float st  = smem[0][0] + smem[0][1] + smem[0][2] + smem[0][3];
        float sst = smem[1][0] + smem[1][1] + smem[1][2] + smem[1][3];
        float mu   = st * (1.0f / HD);
        float var  = sst * (1.0f / HD) - mu * mu;
        float rstd = rsqrtf(var + 1e-12f);
        const float4 wv = reinterpret_cast<const float4*>(lnw)[t];
        const float4 bv = reinterpret_cast<const float4*>(lnb)[t];
        float y0 = (v.x - mu) * rstd * wv.x + bv.x;
        float y1 = (v.y - mu) * rstd * wv.y + bv.y;
        float y2 = (v.z - mu) * rstd * wv.z + bv.z;
        float y3 = (v.w - mu) * rstd * wv.w + bv.w;
        float n2 = wave_sum(y0*y0 + y1*y1 + y2*y2 + y3*y3);
        if (lane == 0) smem[2][wid] = n2;
        __syncthreads();
        float nt2 = smem[2][0] + smem[2][1] + smem[2][2] + smem[2][3];
        float sc = 16.0f / fmaxf(sqrtf(nt2), 1e-12f);   // x16 prescale for fp8
        int r = __builtin_amdgcn_cvt_pk_fp8_f32(y0 * sc, y1 * sc, 0, false);
        r = __builtin_amdgcn_cvt_pk_fp8_f32(y2 * sc, y3 * sc, r, true);
        reinterpret_cast<int*>(Qf + (size_t)b * HD)[t] = r;
    } else if (b < NR + ID) {
        const int row = b - NR;
        const float4 v = reinterpret_cast<const float4*>(kw + (size_t)row * HD)[t];
        float n2 = wave_sum(v.x*v.x + v.y*v.y + v.z*v.z + v.w*v.w);
        if (lane == 0) smem[0][wid] = n2;
        __syncthreads();
        float nt2 = smem[0][0] + smem[0][1] + smem[0][2] + smem[0][3];
        float sc = 16.0f / fmaxf(sqrtf(nt2), 1e-12f);   // x16 prescale for fp8
        int r = __builtin_amdgcn_cvt_pk_fp8_f32(v.x * sc, v.y * sc, 0, false);
        r = __builtin_amdgcn_cvt_pk_fp8_f32(v.z * sc, v.w * sc, r, true);
        reinterpret_cast<int*>(Kf + (size_t)row * HD)[t] = r;
    } else {
        const int b2 = b - NR - ID;
        const int bi = (b2 & 63) * 64, bh = (b2 >> 6) * 64;
        const int r0 = t >> 4, c0 = (t & 15) << 2;
#pragma unroll
        for (int rr = 0; rr < 64; rr += 16) {
            float4 val = *reinterpret_cast<const float4*>(
                &qw[(size_t)(bi + rr + r0) * HD + bh + c0]);
            smem[rr + r0][c0 + 0] = val.x; smem[rr + r0][c0 + 1] = val.y;
            smem[rr + r0][c0 + 2] = val.z; smem[rr + r0][c0 + 3] = val.w;
        }
        __syncthreads();
#pragma unroll
        for (int rr = 0; rr < 64; rr += 16) {
            ushort4 o;
            o.x = f2bf(smem[c0 + 0][rr + r0]);
            o.y = f2bf(smem[c0 + 1][rr + r0]);
            o.z = f2bf(smem[c0 + 2][rr + r0]);
            o.w = f2bf(smem[c0 + 3][rr + r0]);
            *reinterpret_cast<ushort4*>(&VT[(size_t)(bh + rr + r0) * ID + bi + c0]) = o;
        }
    }
}

// ---------------- in-place row l2-normalize + bias ----------------
__global__ __launch_bounds__(256) void outnorm_kernel(
    float* __restrict__ X, const float* __restrict__ bias) {
    __shared__ float red2[4];
    const int row = blockIdx.x, t = threadIdx.x;
    const int lane = t & 63, wid = t >> 6;
    float4 v = reinterpret_cast<float4*>(X + (size_t)row * HD)[t];
    float n2 = wave_sum(v.x*v.x + v.y*v.y + v.z*v.z + v.w*v.w);
    if (lane == 0) red2[wid] = n2;
    __syncthreads();
    float nt = red2[0] + red2[1] + red2[2] + red2[3];
    float sc = 1.0f / fmaxf(sqrtf(nt), 1e-12f);
    const float4 bv = reinterpret_cast<const float4*>(bias)[t];
    float4 o;
    o.x = v.x * sc + bv.x; o.y = v.y * sc + bv.y;
    o.z = v.z * sc + bv.z; o.w = v.w * sc + bv.w;
    reinterpret_cast<float4*>(X + (size_t)row * HD)[t] = o;
}

extern "C" void kernel_launch(void* const* d_in, const int* in_sizes, int n_in,
                              void* d_out, int out_size, void* d_ws, size_t ws_size,
                              hipStream_t stream) {
    const float* hs   = (const float*)d_in[0];  // hidden_states [4,2048,1024]
    const float* lnw  = (const float*)d_in[1];  // ln_weight [1024]
    const float* lnb  = (const float*)d_in[2];  // ln_bias [1024]
    const float* kw   = (const float*)d_in[3];  // k_weight [4096,1024]
    const float* qw   = (const float*)d_in[4];  // q_weight [4096,1024]
    const float* bias = (const float*)d_in[5];  // bias [1024]
    float* out = (float*)d_out;

    char* ws = (char*)d_ws;
    unsigned char* Qf = (unsigned char*)(ws);                       //  8 MiB fp8
    unsigned char* Kf = (unsigned char*)(ws + (size_t)8388608);     //  4 MiB fp8
    ushort* VT   = (ushort*)(ws + (size_t)12582912);                //  8 MiB bf16
    ushort* Bmat = (ushort*)(ws + (size_t)20971520);                // 64 MiB bf16

    // merged prep: 8192 LN rows (fp8) + 4096 K rows (fp8) + 1024 transpose tiles (bf16)
    prep_kernel<<<NR + ID + 1024, 256, 0, stream>>>(hs, lnw, lnb, kw, qw, Qf, Kf, VT);
    // GEMM1: MX-fp8 [8192,1024] x [4096,1024]^T -> act -> Bmat bf16 [8192,4096]
    gemm1f_kernel<<<(NR / 128) * (ID / 128), 256, 0, stream>>>(
        Qf, Kf, Bmat, ID, HD);
    // GEMM2: [8192,4096] x [1024,4096]^T -> out f32 [8192,1024]
    //        triple-buffered counted-vmcnt; grid 256 = 8 xcd * 32 cu
    gemm2t_kernel<<<(NR / 256) * (HD / 128), 512, 0, stream>>>(
        Bmat, VT, out, HD, ID, ID / 64);
    outnorm_kernel<<<NR, 256, 0, stream>>>(out, bias);
}